// Round 2
// baseline (390.305 us; speedup 1.0000x reference)
//
#include <hip/hip_runtime.h>
#include <math.h>

#define DM    1024
#define DH    64
#define NCTX  4096

// workspace layout (float offsets)
#define WS_Q   0
#define WS_K   (NCTX*DH)
#define WS_U   (2*NCTX*DH)   // UT: [DH][NCTX] transposed
#define WS_Y   (3*NCTX*DH)
#define WS_WK  (4*NCTX*DH)   // transposed W_k [DM][DH]

// ---------------- W_kT -> Wk transpose ----------------
__global__ __launch_bounds__(256) void wk_transpose_kernel(
    const float* __restrict__ WkT, float* __restrict__ Wk)
{
  int tg = blockIdx.x * 256 + threadIdx.x;   // 0..65535
  int m = tg >> 6, h = tg & 63;
  Wk[tg] = WkT[h * DM + m];                  // Wk[m][h] = WkT[h][m]
}

// ---------------- projections: Q = x@Wq, K = x@Wk, UT = (x@Wo)^T ----------------
// grid (128 row-tiles, 3 mats), block 256 (4 waves). Wave = 8 rows x 64 cols.
// lane = col. W loads coalesced b32; x loads wave-uniform -> s_load.
__global__ __launch_bounds__(256) void proj_kernel(
    const float* __restrict__ x, const float* __restrict__ Wq,
    const float* __restrict__ Wk, const float* __restrict__ Wo,
    float* __restrict__ Q, float* __restrict__ Kc, float* __restrict__ UT)
{
  const int tid  = threadIdx.x;
  const int lane = tid & 63;
  const int w    = __builtin_amdgcn_readfirstlane(tid >> 6);
  const int mat  = blockIdx.y;
  const int r0   = blockIdx.x * 32 + w * 8;
  const float* __restrict__ Wm = (mat == 0) ? Wq : (mat == 1) ? Wk : Wo;

  float acc[8] = {0.f,0.f,0.f,0.f,0.f,0.f,0.f,0.f};

  for (int k = 0; k < DM; k += 4) {
    float w0 = Wm[(k+0)*DH + lane];
    float w1 = Wm[(k+1)*DH + lane];
    float w2 = Wm[(k+2)*DH + lane];
    float w3 = Wm[(k+3)*DH + lane];
    #pragma unroll
    for (int rr = 0; rr < 8; ++rr) {
      float4 xv = *(const float4*)&x[(r0+rr)*DM + k];   // wave-uniform -> s_load
      acc[rr] += xv.x*w0 + xv.y*w1 + xv.z*w2 + xv.w*w3;
    }
  }

  if (mat == 0) {
    #pragma unroll
    for (int rr = 0; rr < 8; ++rr) Q[(r0+rr)*DH + lane] = acc[rr];
  } else if (mat == 1) {
    #pragma unroll
    for (int rr = 0; rr < 8; ++rr) Kc[(r0+rr)*DH + lane] = acc[rr];
  } else {
    // UT[h][r] = U[r][h]; per-lane 2x float4 contiguous stores
    *(float4*)&UT[lane*NCTX + r0]     = make_float4(acc[0],acc[1],acc[2],acc[3]);
    *(float4*)&UT[lane*NCTX + r0 + 4] = make_float4(acc[4],acc[5],acc[6],acc[7]);
  }
}

// ---------------- flash attention (causal, no scale), f32 ----------------
__device__ __forceinline__ float wave_reduce_max(float v) {
  #pragma unroll
  for (int off = 32; off > 0; off >>= 1)
    v = fmaxf(v, __shfl_xor(v, off, 64));
  return v;
}
__device__ __forceinline__ float wave_reduce_sum(float v) {
  #pragma unroll
  for (int off = 32; off > 0; off >>= 1)
    v += __shfl_xor(v, off, 64);
  return v;
}

// grid 512: block = 4 waves, wave = 2 query rows (K/U tile reads amortized in regs).
__global__ __launch_bounds__(256) void attn_kernel(
    const float* __restrict__ Q, const float* __restrict__ Kc,
    const float* __restrict__ UT, float* __restrict__ Y)
{
  __shared__ float Kt[64][68];    // [key][dim], b128 conflict-free (17d+q mod 8)
  __shared__ float Us[64][68];    // [dim][key], staged from UT row-major
  __shared__ float ps[8][64];     // per-row p vectors

  const int tid  = threadIdx.x;
  const int lane = tid & 63;
  const int w    = __builtin_amdgcn_readfirstlane(tid >> 6);
  const int r_base = 8 * (gridDim.x - 1 - blockIdx.x);  // heaviest blocks first
  const int ra = r_base + w * 2;
  const int rb = ra + 1;

  float4 qa[16], qb[16];
  #pragma unroll
  for (int i = 0; i < 16; ++i) {
    qa[i] = *(const float4*)&Q[ra * DH + i * 4];
    qb[i] = *(const float4*)&Q[rb * DH + i * 4];
  }

  float ma = -INFINITY, la = 0.f, acca = 0.f;
  float mb = -INFINITY, lb = 0.f, accb = 0.f;
  const int nt = (r_base >> 6) + 1;

  for (int t = 0; t < nt; ++t) {
    const int j0 = t * 64;
    __syncthreads();
    #pragma unroll
    for (int it = 0; it < 4; ++it) {
      int a = it * 16 + (tid >> 4);   // 0..63
      int c = tid & 15;
      // K tile: row-major copy
      *(float4*)&Kt[a][c * 4] = *(const float4*)&Kc[(j0 + a) * DH + c * 4];
      // U tile: already transposed in global -> row-major copy
      *(float4*)&Us[a][c * 4] = *(const float4*)&UT[a * NCTX + j0 + c * 4];
    }
    __syncthreads();

    // scores: lane = key j0+lane; K fragment reused for both rows
    float sva = 0.f, svb = 0.f;
    #pragma unroll
    for (int i = 0; i < 16; ++i) {
      float4 k4 = *(const float4*)&Kt[lane][i * 4];
      sva += qa[i].x*k4.x + qa[i].y*k4.y + qa[i].z*k4.z + qa[i].w*k4.w;
      svb += qb[i].x*k4.x + qb[i].y*k4.y + qb[i].z*k4.z + qb[i].w*k4.w;
    }
    float sa = (j0 + lane <= ra) ? sva : -3.0e38f;
    float sb = (j0 + lane <= rb) ? svb : -3.0e38f;

    // online softmax (row a)
    float mna = fmaxf(ma, wave_reduce_max(sa));
    float pa  = (j0 + lane <= ra) ? __expf(sa - mna) : 0.f;
    float tsa = wave_reduce_sum(pa);
    float sca = __expf(ma - mna);
    la = la * sca + tsa;  acca *= sca;  ma = mna;
    // online softmax (row b)
    float mnb = fmaxf(mb, wave_reduce_max(sb));
    float pb  = (j0 + lane <= rb) ? __expf(sb - mnb) : 0.f;
    float tsb = wave_reduce_sum(pb);
    float scb = __expf(mb - mnb);
    lb = lb * scb + tsb;  accb *= scb;  mb = mnb;

    ps[2*w+0][lane] = pa;
    ps[2*w+1][lane] = pb;

    // PV: lane = output dim d; U fragment reused for both rows
    #pragma unroll
    for (int i = 0; i < 16; ++i) {
      float4 u4  = *(const float4*)&Us[lane][i * 4];
      float4 p4a = *(const float4*)&ps[2*w+0][i * 4];   // broadcast
      float4 p4b = *(const float4*)&ps[2*w+1][i * 4];
      acca += p4a.x*u4.x + p4a.y*u4.y + p4a.z*u4.z + p4a.w*u4.w;
      accb += p4b.x*u4.x + p4b.y*u4.y + p4b.z*u4.z + p4b.w*u4.w;
    }
  }
  Y[ra * DH + lane] = acca / la;
  Y[rb * DH + lane] = accb / lb;
}

// ---------------- epilogue: out = Y @ W_vT  ([4096,64]@[64,1024]) ----------------
__global__ __launch_bounds__(256) void out_kernel(
    const float* __restrict__ Y, const float* __restrict__ Wv,
    float* __restrict__ out)
{
  __shared__ float Ws[64][256];
  __shared__ float YsT[64][64];
  const int tid = threadIdx.x;
  const int r0  = blockIdx.x * 64;
  const int cb  = blockIdx.y;           // 0..3
  const int c4  = tid & 63;
  const int rg  = __builtin_amdgcn_readfirstlane(tid >> 6);  // 0..3

  #pragma unroll
  for (int it = 0; it < 16; ++it) {
    int idx = it * 256 + tid;
    int h = idx >> 6, cc = idx & 63;
    *(float4*)&Ws[h][cc * 4] = *(const float4*)&Wv[h * DM + cb * 256 + cc * 4];
  }
  #pragma unroll
  for (int it = 0; it < 4; ++it) {
    int idx = it * 256 + tid;
    int h4 = idx & 15, rr = idx >> 4;
    float4 yv = *(const float4*)&Y[(r0 + rr) * DH + h4 * 4];
    YsT[h4*4+0][rr] = yv.x; YsT[h4*4+1][rr] = yv.y;
    YsT[h4*4+2][rr] = yv.z; YsT[h4*4+3][rr] = yv.w;
  }
  __syncthreads();

  float4 acc[16];
  #pragma unroll
  for (int i = 0; i < 16; ++i) acc[i] = make_float4(0.f, 0.f, 0.f, 0.f);

  #pragma unroll 8
  for (int h = 0; h < 64; ++h) {
    float4 w4 = *(const float4*)&Ws[h][c4 * 4];
    #pragma unroll
    for (int g = 0; g < 4; ++g) {
      float4 y4 = *(const float4*)&YsT[h][rg * 16 + g * 4];  // broadcast
      float ys[4] = {y4.x, y4.y, y4.z, y4.w};
      #pragma unroll
      for (int e = 0; e < 4; ++e) {
        acc[g*4+e].x += ys[e] * w4.x;
        acc[g*4+e].y += ys[e] * w4.y;
        acc[g*4+e].z += ys[e] * w4.z;
        acc[g*4+e].w += ys[e] * w4.w;
      }
    }
  }
  #pragma unroll
  for (int i = 0; i < 16; ++i)
    *(float4*)&out[(r0 + rg * 16 + i) * DM + cb * 256 + c4 * 4] = acc[i];
}

extern "C" void kernel_launch(void* const* d_in, const int* in_sizes, int n_in,
                              void* d_out, int out_size, void* d_ws, size_t ws_size,
                              hipStream_t stream) {
  const float* x   = (const float*)d_in[0];
  const float* Wq  = (const float*)d_in[1];
  const float* WkT = (const float*)d_in[2];
  const float* Wo  = (const float*)d_in[3];
  const float* Wv  = (const float*)d_in[4];
  float* out = (float*)d_out;
  float* ws  = (float*)d_ws;
  float* Q   = ws + WS_Q;
  float* Kc  = ws + WS_K;
  float* UT  = ws + WS_U;
  float* Y   = ws + WS_Y;
  float* Wk  = ws + WS_WK;

  hipLaunchKernelGGL(wk_transpose_kernel, dim3(256), dim3(256), 0, stream, WkT, Wk);
  hipLaunchKernelGGL(proj_kernel, dim3(128, 3), dim3(256), 0, stream,
                     x, Wq, Wk, Wo, Q, Kc, UT);
  hipLaunchKernelGGL(attn_kernel, dim3(512), dim3(256), 0, stream, Q, Kc, UT, Y);
  hipLaunchKernelGGL(out_kernel, dim3(64, 4), dim3(256), 0, stream, Y, Wv, out);
}

// Round 8
// 384.062 us; speedup vs baseline: 1.0163x; 1.0163x over previous
//
#include <hip/hip_runtime.h>
#include <math.h>

#define DM    1024
#define DH    64
#define NCTX  4096

// workspace layout (float offsets) — 4,456,448 bytes total, round-2-proven
#define WS_Q   0
#define WS_K   (NCTX*DH)
#define WS_U   (2*NCTX*DH)   // UT: [DH][NCTX] transposed
#define WS_Y   (3*NCTX*DH)
#define WS_WK  (4*NCTX*DH)   // transposed W_k [DM][DH]

// ---------------- W_kT -> Wk transpose ----------------
__global__ __launch_bounds__(256) void wk_transpose_kernel(
    const float* __restrict__ WkT, float* __restrict__ Wk)
{
  int tg = blockIdx.x * 256 + threadIdx.x;   // 0..65535
  int m = tg >> 6, h = tg & 63;
  Wk[tg] = WkT[h * DM + m];                  // Wk[m][h] = WkT[h][m]
}

// ---------------- projections: Q = x@Wq, K = x@Wk, UT = (x@Wo)^T ----------------
// grid (128 row-tiles, 3 mats), block 256 (4 waves). Wave = 8 rows x 64 cols.
__global__ __launch_bounds__(256) void proj_kernel(
    const float* __restrict__ x, const float* __restrict__ Wq,
    const float* __restrict__ Wk, const float* __restrict__ Wo,
    float* __restrict__ Q, float* __restrict__ Kc, float* __restrict__ UT)
{
  const int tid  = threadIdx.x;
  const int lane = tid & 63;
  const int w    = __builtin_amdgcn_readfirstlane(tid >> 6);
  const int mat  = blockIdx.y;
  const int r0   = blockIdx.x * 32 + w * 8;
  const float* __restrict__ Wm = (mat == 0) ? Wq : (mat == 1) ? Wk : Wo;

  float acc[8] = {0.f,0.f,0.f,0.f,0.f,0.f,0.f,0.f};

  for (int k = 0; k < DM; k += 4) {
    float w0 = Wm[(k+0)*DH + lane];
    float w1 = Wm[(k+1)*DH + lane];
    float w2 = Wm[(k+2)*DH + lane];
    float w3 = Wm[(k+3)*DH + lane];
    #pragma unroll
    for (int rr = 0; rr < 8; ++rr) {
      float4 xv = *(const float4*)&x[(r0+rr)*DM + k];   // wave-uniform -> s_load
      acc[rr] += xv.x*w0 + xv.y*w1 + xv.z*w2 + xv.w*w3;
    }
  }

  if (mat == 0) {
    #pragma unroll
    for (int rr = 0; rr < 8; ++rr) Q[(r0+rr)*DH + lane] = acc[rr];
  } else if (mat == 1) {
    #pragma unroll
    for (int rr = 0; rr < 8; ++rr) Kc[(r0+rr)*DH + lane] = acc[rr];
  } else {
    // UT[h][r] = U[r][h]; per-lane 2x float4 contiguous stores
    *(float4*)&UT[lane*NCTX + r0]     = make_float4(acc[0],acc[1],acc[2],acc[3]);
    *(float4*)&UT[lane*NCTX + r0 + 4] = make_float4(acc[4],acc[5],acc[6],acc[7]);
  }
}

// ---------------- flash attention (causal, no scale), f32 ----------------
__device__ __forceinline__ float wave_reduce_max(float v) {
  #pragma unroll
  for (int off = 32; off > 0; off >>= 1)
    v = fmaxf(v, __shfl_xor(v, off, 64));
  return v;
}
__device__ __forceinline__ float wave_reduce_sum(float v) {
  #pragma unroll
  for (int off = 32; off > 0; off >>= 1)
    v += __shfl_xor(v, off, 64);
  return v;
}

// grid 512: block = 4 waves. Wave W = blockIdx*4+w handles rows
//   ra = W (light, 0..2047) and rb = 4095-W (heavy, 2048..4095)
// => per-wave tile count ~const (balance by construction).
// All waves loop to block-uniform ntB; tiles past a row's causal range are
// exact no-ops (all lanes masked -> p=0, tsum=0, m_new=m, scale=1).
__global__ __launch_bounds__(256) void attn_kernel(
    const float* __restrict__ Q, const float* __restrict__ Kc,
    const float* __restrict__ UT, float* __restrict__ Y)
{
  __shared__ float Kt[64][68];    // [key][dim], padded
  __shared__ float Us[64][68];    // [dim][key], staged from UT row-major
  __shared__ float ps[8][64];     // per-row p vectors

  const int tid  = threadIdx.x;
  const int lane = tid & 63;
  const int w    = __builtin_amdgcn_readfirstlane(tid >> 6);
  const int ra = blockIdx.x * 4 + w;       // light row
  const int rb = (NCTX - 1) - ra;          // heavy row
  // block-uniform tile bound: max rb in block is for w=0 -> 4095 - 4*blockIdx
  const int ntB = (((NCTX - 1) - blockIdx.x * 4) >> 6) + 1;

  float4 qa[16], qb[16];
  #pragma unroll
  for (int i = 0; i < 16; ++i) {
    qa[i] = *(const float4*)&Q[ra * DH + i * 4];
    qb[i] = *(const float4*)&Q[rb * DH + i * 4];
  }

  float ma = -INFINITY, la = 0.f, acca = 0.f;
  float mb = -INFINITY, lb = 0.f, accb = 0.f;

  for (int t = 0; t < ntB; ++t) {
    const int j0 = t * 64;
    __syncthreads();
    #pragma unroll
    for (int it = 0; it < 4; ++it) {
      int a = it * 16 + (tid >> 4);   // 0..63
      int c = tid & 15;
      // K tile: row-major copy
      *(float4*)&Kt[a][c * 4] = *(const float4*)&Kc[(j0 + a) * DH + c * 4];
      // U tile: already transposed in global -> row-major copy
      *(float4*)&Us[a][c * 4] = *(const float4*)&UT[a * NCTX + j0 + c * 4];
    }
    __syncthreads();

    // scores: lane = key j0+lane; K fragment reused for both rows
    float sva = 0.f, svb = 0.f;
    #pragma unroll
    for (int i = 0; i < 16; ++i) {
      float4 k4 = *(const float4*)&Kt[lane][i * 4];
      sva += qa[i].x*k4.x + qa[i].y*k4.y + qa[i].z*k4.z + qa[i].w*k4.w;
      svb += qb[i].x*k4.x + qb[i].y*k4.y + qb[i].z*k4.z + qb[i].w*k4.w;
    }
    float sa = (j0 + lane <= ra) ? sva : -3.0e38f;
    float sb = (j0 + lane <= rb) ? svb : -3.0e38f;

    // online softmax (row a)
    float mna = fmaxf(ma, wave_reduce_max(sa));
    float pa  = (j0 + lane <= ra) ? __expf(sa - mna) : 0.f;
    float tsa = wave_reduce_sum(pa);
    float sca = __expf(ma - mna);
    la = la * sca + tsa;  acca *= sca;  ma = mna;
    // online softmax (row b)
    float mnb = fmaxf(mb, wave_reduce_max(sb));
    float pb  = (j0 + lane <= rb) ? __expf(sb - mnb) : 0.f;
    float tsb = wave_reduce_sum(pb);
    float scb = __expf(mb - mnb);
    lb = lb * scb + tsb;  accb *= scb;  mb = mnb;

    ps[2*w+0][lane] = pa;
    ps[2*w+1][lane] = pb;

    // PV: lane = output dim d; U fragment reused for both rows
    #pragma unroll
    for (int i = 0; i < 16; ++i) {
      float4 u4  = *(const float4*)&Us[lane][i * 4];
      float4 p4a = *(const float4*)&ps[2*w+0][i * 4];   // broadcast
      float4 p4b = *(const float4*)&ps[2*w+1][i * 4];
      acca += p4a.x*u4.x + p4a.y*u4.y + p4a.z*u4.z + p4a.w*u4.w;
      accb += p4b.x*u4.x + p4b.y*u4.y + p4b.z*u4.z + p4b.w*u4.w;
    }
  }
  Y[ra * DH + lane] = acca / la;
  Y[rb * DH + lane] = accb / lb;
}

// ---------------- epilogue: out = Y @ W_vT  ([4096,64]@[64,1024]) ----------------
__global__ __launch_bounds__(256) void out_kernel(
    const float* __restrict__ Y, const float* __restrict__ Wv,
    float* __restrict__ out)
{
  __shared__ float Ws[64][256];
  __shared__ float YsT[64][64];
  const int tid = threadIdx.x;
  const int r0  = blockIdx.x * 64;
  const int cb  = blockIdx.y;           // 0..3
  const int c4  = tid & 63;
  const int rg  = __builtin_amdgcn_readfirstlane(tid >> 6);  // 0..3

  #pragma unroll
  for (int it = 0; it < 16; ++it) {
    int idx = it * 256 + tid;
    int h = idx >> 6, cc = idx & 63;
    *(float4*)&Ws[h][cc * 4] = *(const float4*)&Wv[h * DM + cb * 256 + cc * 4];
  }
  #pragma unroll
  for (int it = 0; it < 4; ++it) {
    int idx = it * 256 + tid;
    int h4 = idx & 15, rr = idx >> 4;
    float4 yv = *(const float4*)&Y[(r0 + rr) * DH + h4 * 4];
    YsT[h4*4+0][rr] = yv.x; YsT[h4*4+1][rr] = yv.y;
    YsT[h4*4+2][rr] = yv.z; YsT[h4*4+3][rr] = yv.w;
  }
  __syncthreads();

  float4 acc[16];
  #pragma unroll
  for (int i = 0; i < 16; ++i) acc[i] = make_float4(0.f, 0.f, 0.f, 0.f);

  #pragma unroll 8
  for (int h = 0; h < 64; ++h) {
    float4 w4 = *(const float4*)&Ws[h][c4 * 4];
    #pragma unroll
    for (int g = 0; g < 4; ++g) {
      float4 y4 = *(const float4*)&YsT[h][rg * 16 + g * 4];  // broadcast
      float ys[4] = {y4.x, y4.y, y4.z, y4.w};
      #pragma unroll
      for (int e = 0; e < 4; ++e) {
        acc[g*4+e].x += ys[e] * w4.x;
        acc[g*4+e].y += ys[e] * w4.y;
        acc[g*4+e].z += ys[e] * w4.z;
        acc[g*4+e].w += ys[e] * w4.w;
      }
    }
  }
  #pragma unroll
  for (int i = 0; i < 16; ++i)
    *(float4*)&out[(r0 + rg * 16 + i) * DM + cb * 256 + c4 * 4] = acc[i];
}

extern "C" void kernel_launch(void* const* d_in, const int* in_sizes, int n_in,
                              void* d_out, int out_size, void* d_ws, size_t ws_size,
                              hipStream_t stream) {
  const float* x   = (const float*)d_in[0];
  const float* Wq  = (const float*)d_in[1];
  const float* WkT = (const float*)d_in[2];
  const float* Wo  = (const float*)d_in[3];
  const float* Wv  = (const float*)d_in[4];
  float* out = (float*)d_out;
  float* ws  = (float*)d_ws;
  float* Q   = ws + WS_Q;
  float* Kc  = ws + WS_K;
  float* UT  = ws + WS_U;
  float* Y   = ws + WS_Y;
  float* Wk  = ws + WS_WK;

  hipLaunchKernelGGL(wk_transpose_kernel, dim3(256), dim3(256), 0, stream, WkT, Wk);
  hipLaunchKernelGGL(proj_kernel, dim3(128, 3), dim3(256), 0, stream,
                     x, Wq, Wk, Wo, Q, Kc, UT);
  hipLaunchKernelGGL(attn_kernel, dim3(512), dim3(256), 0, stream, Q, Kc, UT, Y);
  hipLaunchKernelGGL(out_kernel, dim3(64, 4), dim3(256), 0, stream, Y, Wv, out);
}

// Round 9
// 267.876 us; speedup vs baseline: 1.4570x; 1.4337x over previous
//
#include <hip/hip_runtime.h>
#include <math.h>

#define DM    1024
#define DH    64
#define NCTX  4096

// workspace layout (float offsets) — first 4,456,448 bytes proven in round 2
#define WS_Q   0
#define WS_K   (NCTX*DH)
#define WS_U   (2*NCTX*DH)   // UT: [DH][NCTX] transposed
#define WS_Y   (3*NCTX*DH)
#define WS_WK  (4*NCTX*DH)   // transposed W_k [DM][DH]
#define WS_PROVEN_BYTES 4456448
// partials: Pm 64KB, Pl 64KB, Py 4MB  (placed in ws if room, else d_out)
#define PART_BYTES (65536 + 65536 + 4194304)

// ---------------- W_kT -> Wk transpose ----------------
__global__ __launch_bounds__(256) void wk_transpose_kernel(
    const float* __restrict__ WkT, float* __restrict__ Wk)
{
  int tg = blockIdx.x * 256 + threadIdx.x;   // 0..65535
  int m = tg >> 6, h = tg & 63;
  Wk[tg] = WkT[h * DM + m];                  // Wk[m][h] = WkT[h][m]
}

// ---------------- projections: Q = x@Wq, K = x@Wk, UT = (x@Wo)^T ----------------
__global__ __launch_bounds__(256) void proj_kernel(
    const float* __restrict__ x, const float* __restrict__ Wq,
    const float* __restrict__ Wk, const float* __restrict__ Wo,
    float* __restrict__ Q, float* __restrict__ Kc, float* __restrict__ UT)
{
  const int tid  = threadIdx.x;
  const int lane = tid & 63;
  const int w    = __builtin_amdgcn_readfirstlane(tid >> 6);
  const int mat  = blockIdx.y;
  const int r0   = blockIdx.x * 32 + w * 8;
  const float* __restrict__ Wm = (mat == 0) ? Wq : (mat == 1) ? Wk : Wo;

  float acc[8] = {0.f,0.f,0.f,0.f,0.f,0.f,0.f,0.f};

  for (int k = 0; k < DM; k += 4) {
    float w0 = Wm[(k+0)*DH + lane];
    float w1 = Wm[(k+1)*DH + lane];
    float w2 = Wm[(k+2)*DH + lane];
    float w3 = Wm[(k+3)*DH + lane];
    #pragma unroll
    for (int rr = 0; rr < 8; ++rr) {
      float4 xv = *(const float4*)&x[(r0+rr)*DM + k];   // wave-uniform -> s_load
      acc[rr] += xv.x*w0 + xv.y*w1 + xv.z*w2 + xv.w*w3;
    }
  }

  if (mat == 0) {
    #pragma unroll
    for (int rr = 0; rr < 8; ++rr) Q[(r0+rr)*DH + lane] = acc[rr];
  } else if (mat == 1) {
    #pragma unroll
    for (int rr = 0; rr < 8; ++rr) Kc[(r0+rr)*DH + lane] = acc[rr];
  } else {
    *(float4*)&UT[lane*NCTX + r0]     = make_float4(acc[0],acc[1],acc[2],acc[3]);
    *(float4*)&UT[lane*NCTX + r0 + 4] = make_float4(acc[4],acc[5],acc[6],acc[7]);
  }
}

// ---------------- flash attention (causal, no scale), f32, split-K x4 ----------------
__device__ __forceinline__ float wave_reduce_max(float v) {
  #pragma unroll
  for (int off = 32; off > 0; off >>= 1)
    v = fmaxf(v, __shfl_xor(v, off, 64));
  return v;
}
__device__ __forceinline__ float wave_reduce_sum(float v) {
  #pragma unroll
  for (int off = 32; off > 0; off >>= 1)
    v += __shfl_xor(v, off, 64);
  return v;
}

// grid (512, 4): block (pb, c) = green block pb, key-chunk c of [0, T):
// tiles [c*T/4, (c+1)*T/4), T = heavy row's tile count. Wave w handles rows
// ra = 4*pb+w (light) and rb = 4095-ra (heavy). Inner body identical to the
// round-8 PASS; tiles outside a row's causal range are exact no-ops.
// Outputs per-chunk partials (m, l, unnormalized y).
__global__ __launch_bounds__(256) void attn_kernel(
    const float* __restrict__ Q, const float* __restrict__ Kc,
    const float* __restrict__ UT,
    float* __restrict__ Pm, float* __restrict__ Pl, float* __restrict__ Py)
{
  __shared__ float Kt[64][68];    // [key][dim], padded
  __shared__ float Us[64][68];    // [dim][key], staged from UT row-major
  __shared__ float ps[8][64];     // per-row p vectors

  const int tid  = threadIdx.x;
  const int lane = tid & 63;
  const int w    = __builtin_amdgcn_readfirstlane(tid >> 6);
  const int pb   = blockIdx.x;            // 0..511
  const int c    = blockIdx.y;            // 0..3
  const int ra = pb * 4 + w;              // light row
  const int rb = (NCTX - 1) - ra;         // heavy row
  const int T  = (((NCTX - 1) - pb * 4) >> 6) + 1;   // block-uniform tile count
  const int t0 = (c * T) >> 2, t1 = ((c + 1) * T) >> 2;

  float4 qa[16], qb[16];
  #pragma unroll
  for (int i = 0; i < 16; ++i) {
    qa[i] = *(const float4*)&Q[ra * DH + i * 4];
    qb[i] = *(const float4*)&Q[rb * DH + i * 4];
  }

  float ma = -INFINITY, la = 0.f, acca = 0.f;
  float mb = -INFINITY, lb = 0.f, accb = 0.f;

  for (int t = t0; t < t1; ++t) {
    const int j0 = t * 64;
    __syncthreads();
    #pragma unroll
    for (int it = 0; it < 4; ++it) {
      int a = it * 16 + (tid >> 4);   // 0..63
      int cc = tid & 15;
      *(float4*)&Kt[a][cc * 4] = *(const float4*)&Kc[(j0 + a) * DH + cc * 4];
      *(float4*)&Us[a][cc * 4] = *(const float4*)&UT[a * NCTX + j0 + cc * 4];
    }
    __syncthreads();

    // scores: lane = key j0+lane; K fragment reused for both rows
    float sva = 0.f, svb = 0.f;
    #pragma unroll
    for (int i = 0; i < 16; ++i) {
      float4 k4 = *(const float4*)&Kt[lane][i * 4];
      sva += qa[i].x*k4.x + qa[i].y*k4.y + qa[i].z*k4.z + qa[i].w*k4.w;
      svb += qb[i].x*k4.x + qb[i].y*k4.y + qb[i].z*k4.z + qb[i].w*k4.w;
    }
    float sa = (j0 + lane <= ra) ? sva : -3.0e38f;
    float sb = (j0 + lane <= rb) ? svb : -3.0e38f;

    // online softmax (row a)
    float mna = fmaxf(ma, wave_reduce_max(sa));
    float pa  = (j0 + lane <= ra) ? __expf(sa - mna) : 0.f;
    float tsa = wave_reduce_sum(pa);
    float sca = __expf(ma - mna);
    la = la * sca + tsa;  acca *= sca;  ma = mna;
    // online softmax (row b)
    float mnb = fmaxf(mb, wave_reduce_max(sb));
    float pb_  = (j0 + lane <= rb) ? __expf(sb - mnb) : 0.f;
    float tsb = wave_reduce_sum(pb_);
    float scb = __expf(mb - mnb);
    lb = lb * scb + tsb;  accb *= scb;  mb = mnb;

    ps[2*w+0][lane] = pa;
    ps[2*w+1][lane] = pb_;

    // PV: lane = output dim d; U fragment reused for both rows
    #pragma unroll
    for (int i = 0; i < 16; ++i) {
      float4 u4  = *(const float4*)&Us[lane][i * 4];
      float4 p4a = *(const float4*)&ps[2*w+0][i * 4];   // broadcast
      float4 p4b = *(const float4*)&ps[2*w+1][i * 4];
      acca += p4a.x*u4.x + p4a.y*u4.y + p4a.z*u4.z + p4a.w*u4.w;
      accb += p4b.x*u4.x + p4b.y*u4.y + p4b.z*u4.z + p4b.w*u4.w;
    }
  }
  // per-chunk partials (unnormalized y; empty-for-this-row chunks: m=-inf, l=0, y=0)
  Py[(c * NCTX + ra) * DH + lane] = acca;
  Py[(c * NCTX + rb) * DH + lane] = accb;
  if (lane == 0) {
    Pm[c * NCTX + ra] = ma;  Pl[c * NCTX + ra] = la;
    Pm[c * NCTX + rb] = mb;  Pl[c * NCTX + rb] = lb;
  }
}

// ---------------- combine split-K partials ----------------
__global__ __launch_bounds__(256) void combine_kernel(
    const float* __restrict__ Pm, const float* __restrict__ Pl,
    const float* __restrict__ Py, float* __restrict__ Y)
{
  int idx = blockIdx.x * 256 + threadIdx.x;   // 0..262143
  int r = idx >> 6, d = idx & 63;
  float m0 = Pm[0*NCTX + r], m1 = Pm[1*NCTX + r];
  float m2 = Pm[2*NCTX + r], m3 = Pm[3*NCTX + r];
  float M = fmaxf(fmaxf(m0, m1), fmaxf(m2, m3));
  float s0 = __expf(m0 - M), s1 = __expf(m1 - M);
  float s2 = __expf(m2 - M), s3 = __expf(m3 - M);
  float den = s0 * Pl[0*NCTX + r] + s1 * Pl[1*NCTX + r]
            + s2 * Pl[2*NCTX + r] + s3 * Pl[3*NCTX + r];
  float num = s0 * Py[(0*NCTX + r)*DH + d] + s1 * Py[(1*NCTX + r)*DH + d]
            + s2 * Py[(2*NCTX + r)*DH + d] + s3 * Py[(3*NCTX + r)*DH + d];
  Y[idx] = num / den;
}

// ---------------- epilogue: out = Y @ W_vT  ([4096,64]@[64,1024]) ----------------
__global__ __launch_bounds__(256) void out_kernel(
    const float* __restrict__ Y, const float* __restrict__ Wv,
    float* __restrict__ out)
{
  __shared__ float Ws[64][256];
  __shared__ float YsT[64][64];
  const int tid = threadIdx.x;
  const int r0  = blockIdx.x * 64;
  const int cb  = blockIdx.y;           // 0..3
  const int c4  = tid & 63;
  const int rg  = __builtin_amdgcn_readfirstlane(tid >> 6);  // 0..3

  #pragma unroll
  for (int it = 0; it < 16; ++it) {
    int idx = it * 256 + tid;
    int h = idx >> 6, cc = idx & 63;
    *(float4*)&Ws[h][cc * 4] = *(const float4*)&Wv[h * DM + cb * 256 + cc * 4];
  }
  #pragma unroll
  for (int it = 0; it < 4; ++it) {
    int idx = it * 256 + tid;
    int h4 = idx & 15, rr = idx >> 4;
    float4 yv = *(const float4*)&Y[(r0 + rr) * DH + h4 * 4];
    YsT[h4*4+0][rr] = yv.x; YsT[h4*4+1][rr] = yv.y;
    YsT[h4*4+2][rr] = yv.z; YsT[h4*4+3][rr] = yv.w;
  }
  __syncthreads();

  float4 acc[16];
  #pragma unroll
  for (int i = 0; i < 16; ++i) acc[i] = make_float4(0.f, 0.f, 0.f, 0.f);

  #pragma unroll 8
  for (int h = 0; h < 64; ++h) {
    float4 w4 = *(const float4*)&Ws[h][c4 * 4];
    #pragma unroll
    for (int g = 0; g < 4; ++g) {
      float4 y4 = *(const float4*)&YsT[h][rg * 16 + g * 4];  // broadcast
      float ys[4] = {y4.x, y4.y, y4.z, y4.w};
      #pragma unroll
      for (int e = 0; e < 4; ++e) {
        acc[g*4+e].x += ys[e] * w4.x;
        acc[g*4+e].y += ys[e] * w4.y;
        acc[g*4+e].z += ys[e] * w4.z;
        acc[g*4+e].w += ys[e] * w4.w;
      }
    }
  }
  #pragma unroll
  for (int i = 0; i < 16; ++i)
    *(float4*)&out[(r0 + rg * 16 + i) * DM + cb * 256 + c4 * 4] = acc[i];
}

extern "C" void kernel_launch(void* const* d_in, const int* in_sizes, int n_in,
                              void* d_out, int out_size, void* d_ws, size_t ws_size,
                              hipStream_t stream) {
  const float* x   = (const float*)d_in[0];
  const float* Wq  = (const float*)d_in[1];
  const float* WkT = (const float*)d_in[2];
  const float* Wo  = (const float*)d_in[3];
  const float* Wv  = (const float*)d_in[4];
  float* out = (float*)d_out;
  float* ws  = (float*)d_ws;
  float* Q   = ws + WS_Q;
  float* Kc  = ws + WS_K;
  float* UT  = ws + WS_U;
  float* Y   = ws + WS_Y;
  float* Wk  = ws + WS_WK;

  // partials: in ws past the proven region if it fits, else in d_out
  // (d_out is fully overwritten by out_kernel afterwards)
  char* pbase = (ws_size >= (size_t)WS_PROVEN_BYTES + PART_BYTES)
                ? ((char*)d_ws + WS_PROVEN_BYTES) : (char*)d_out;
  float* Pm = (float*)pbase;                       // 4*NCTX f32
  float* Pl = (float*)(pbase + 65536);             // 4*NCTX f32
  float* Py = (float*)(pbase + 131072);            // 4*NCTX*DH f32

  hipLaunchKernelGGL(wk_transpose_kernel, dim3(256), dim3(256), 0, stream, WkT, Wk);
  hipLaunchKernelGGL(proj_kernel, dim3(128, 3), dim3(256), 0, stream,
                     x, Wq, Wk, Wo, Q, Kc, UT);
  hipLaunchKernelGGL(attn_kernel, dim3(512, 4), dim3(256), 0, stream,
                     Q, Kc, UT, Pm, Pl, Py);
  hipLaunchKernelGGL(combine_kernel, dim3(1024), dim3(256), 0, stream,
                     Pm, Pl, Py, Y);
  hipLaunchKernelGGL(out_kernel, dim3(64, 4), dim3(256), 0, stream, Y, Wv, out);
}

// Round 10
// 183.389 us; speedup vs baseline: 2.1283x; 1.4607x over previous
//
#include <hip/hip_runtime.h>
#include <hip/hip_bf16.h>
#include <math.h>

#define DM    1024
#define DH    64
#define NCTX  4096
#define NCH   8        // key-chunks per q-group

typedef __attribute__((ext_vector_type(8))) short bf16x8;
typedef __attribute__((ext_vector_type(4))) float f32x4;

// ---- ws (proven 4,456,448 B): f32 Q, K, UT, Y, Wk (round-2 layout)
#define WS_Q   0
#define WS_K   (NCTX*DH)
#define WS_U   (2*NCTX*DH)
#define WS_Y   (3*NCTX*DH)
#define WS_WK  (4*NCTX*DH)

// ---- d_out scratch (16 MiB, fully overwritten by out_kernel last)
#define D_QH   0          // 512 KiB each: bf16 digit arrays
#define D_QM   524288
#define D_QL   1048576
#define D_KH   1572864
#define D_KM   2097152
#define D_KL   2621440
#define D_UTB  3145728    // 512 KiB bf16 UT
#define D_PY   3670016    // 8 MiB f32 Py [NCH][NCTX][DH]
#define D_PM   12058624   // 128 KiB f32 [NCH][NCTX]
#define D_PL   12189696   // 128 KiB f32  (end 12320768 < 16 MiB)

__device__ __forceinline__ ushort f2bf(float x) {
  __hip_bfloat16 h = __float2bfloat16(x);
  return __builtin_bit_cast(ushort, h);
}
__device__ __forceinline__ float bf2f(ushort u) {
  __hip_bfloat16 h = __builtin_bit_cast(__hip_bfloat16, u);
  return __bfloat162float(h);
}

// ---------------- W_kT -> Wk transpose ----------------
__global__ __launch_bounds__(256) void wk_transpose_kernel(
    const float* __restrict__ WkT, float* __restrict__ Wk)
{
  int tg = blockIdx.x * 256 + threadIdx.x;
  int m = tg >> 6, h = tg & 63;
  Wk[tg] = WkT[h * DM + m];
}

// ---------------- projections (green, unchanged) ----------------
__global__ __launch_bounds__(256) void proj_kernel(
    const float* __restrict__ x, const float* __restrict__ Wq,
    const float* __restrict__ Wk, const float* __restrict__ Wo,
    float* __restrict__ Q, float* __restrict__ Kc, float* __restrict__ UT)
{
  const int tid  = threadIdx.x;
  const int lane = tid & 63;
  const int w    = __builtin_amdgcn_readfirstlane(tid >> 6);
  const int mat  = blockIdx.y;
  const int r0   = blockIdx.x * 32 + w * 8;
  const float* __restrict__ Wm = (mat == 0) ? Wq : (mat == 1) ? Wk : Wo;

  float acc[8] = {0.f,0.f,0.f,0.f,0.f,0.f,0.f,0.f};

  for (int k = 0; k < DM; k += 4) {
    float w0 = Wm[(k+0)*DH + lane];
    float w1 = Wm[(k+1)*DH + lane];
    float w2 = Wm[(k+2)*DH + lane];
    float w3 = Wm[(k+3)*DH + lane];
    #pragma unroll
    for (int rr = 0; rr < 8; ++rr) {
      float4 xv = *(const float4*)&x[(r0+rr)*DM + k];
      acc[rr] += xv.x*w0 + xv.y*w1 + xv.z*w2 + xv.w*w3;
    }
  }

  if (mat == 0) {
    #pragma unroll
    for (int rr = 0; rr < 8; ++rr) Q[(r0+rr)*DH + lane] = acc[rr];
  } else if (mat == 1) {
    #pragma unroll
    for (int rr = 0; rr < 8; ++rr) Kc[(r0+rr)*DH + lane] = acc[rr];
  } else {
    *(float4*)&UT[lane*NCTX + r0]     = make_float4(acc[0],acc[1],acc[2],acc[3]);
    *(float4*)&UT[lane*NCTX + r0 + 4] = make_float4(acc[4],acc[5],acc[6],acc[7]);
  }
}

// ---------------- 3-way bf16 digit split (validated r5-r7) ----------------
__global__ __launch_bounds__(256) void split_kernel(
    const float* __restrict__ Q, const float* __restrict__ K, const float* __restrict__ UT,
    ushort* __restrict__ Qh, ushort* __restrict__ Qm, ushort* __restrict__ Ql,
    ushort* __restrict__ Kh, ushort* __restrict__ Km, ushort* __restrict__ Kl,
    ushort* __restrict__ UTb)
{
  int i = blockIdx.x * 256 + threadIdx.x;
  float q = Q[i];
  ushort h = f2bf(q); float fh = bf2f(h);
  ushort m = f2bf(q - fh); float fm = bf2f(m);
  ushort l = f2bf(q - fh - fm);
  Qh[i] = h; Qm[i] = m; Ql[i] = l;
  float k = K[i];
  h = f2bf(k); fh = bf2f(h);
  m = f2bf(k - fh); fm = bf2f(m);
  l = f2bf(k - fh - fm);
  Kh[i] = h; Km[i] = m; Kl[i] = l;
  UTb[i] = f2bf(UT[i]);
}

// ---------------- MFMA flash attention on the GREEN scaffold ----------------
// 512 blocks x 4 waves, NO block barriers. Wave = unit u = 4*blockIdx+w:
//   g = 255 - (u>>3) (16-row q-group, heavy first), c = u&7 (key-chunk),
//   tiles [c*Tg/8, (c+1)*Tg/8) of THIS group's range.
// Compute blocks verbatim from the r5-r7 validated trio; causal mask applied
// unconditionally every tile. Partials in green row-major layout.
__global__ __launch_bounds__(256) void attn_kernel(
    const ushort* __restrict__ Qh, const ushort* __restrict__ Qm, const ushort* __restrict__ Ql,
    const ushort* __restrict__ Kh, const ushort* __restrict__ Km, const ushort* __restrict__ Kl,
    const ushort* __restrict__ UTb,
    float* __restrict__ Pm, float* __restrict__ Pl, float* __restrict__ Py)
{
  __shared__ __align__(16) ushort ps[4][16*72];   // per-wave P tile [16 q][64+8 keys]
  const int tid  = threadIdx.x;
  const int lane = tid & 63;
  const int w    = tid >> 6;
  ushort* psw = ps[w];
  const int q16  = lane & 15;   // q-within-group (score C/D col; PV B col)
  const int grp  = lane >> 4;   // lane k-group
  const int colb = grp * 8;

  const int u  = blockIdx.x * 4 + w;           // 0..2047
  const int g  = 255 - (u >> 3);               // heavy groups first
  const int c  = u & 7;
  const int Tg = ((16*g + 15) >> 6) + 1;
  const int t0 = (c * Tg) >> 3, t1 = ((c+1) * Tg) >> 3;
  const int q0 = 16 * g;
  const int q  = q0 + q16;

  // Q fragments (3 digits x 2 k-steps)
  bf16x8 fqh[2], fqm[2], fql[2];
  #pragma unroll
  for (int ks = 0; ks < 2; ++ks) {
    int off = (q0 + q16)*DH + 32*ks + colb;
    fqh[ks] = *(const bf16x8*)&Qh[off];
    fqm[ks] = *(const bf16x8*)&Qm[off];
    fql[ks] = *(const bf16x8*)&Ql[off];
  }

  float mrun = -3.0e38f, lrun = 0.f;
  f32x4 yacc[4] = {{0,0,0,0},{0,0,0,0},{0,0,0,0},{0,0,0,0}};

  for (int t = t0; t < t1; ++t) {
    const int j0 = t * 64;
    f32x4 sa[4];
    // scores S^T = K x Q^T: D[key][q], 6-product digit expansion (validated)
    #pragma unroll
    for (int st = 0; st < 4; ++st) {
      f32x4 acc = {0,0,0,0};
      #pragma unroll
      for (int ks = 0; ks < 2; ++ks) {
        int off = (j0 + 16*st + q16)*DH + 32*ks + colb;
        bf16x8 kh = *(const bf16x8*)&Kh[off];
        bf16x8 km = *(const bf16x8*)&Km[off];
        bf16x8 kl = *(const bf16x8*)&Kl[off];
        acc = __builtin_amdgcn_mfma_f32_16x16x32_bf16(kh, fqh[ks], acc, 0,0,0);
        acc = __builtin_amdgcn_mfma_f32_16x16x32_bf16(kh, fqm[ks], acc, 0,0,0);
        acc = __builtin_amdgcn_mfma_f32_16x16x32_bf16(km, fqh[ks], acc, 0,0,0);
        acc = __builtin_amdgcn_mfma_f32_16x16x32_bf16(km, fqm[ks], acc, 0,0,0);
        acc = __builtin_amdgcn_mfma_f32_16x16x32_bf16(kh, fql[ks], acc, 0,0,0);
        acc = __builtin_amdgcn_mfma_f32_16x16x32_bf16(kl, fqh[ks], acc, 0,0,0);
      }
      sa[st] = acc;
    }
    // unconditional causal mask: C/D row = key = j0+16st+4grp+r, col = q
    #pragma unroll
    for (int st = 0; st < 4; ++st)
      #pragma unroll
      for (int r = 0; r < 4; ++r) {
        int key = j0 + 16*st + 4*grp + r;
        if (key > q) sa[st][r] = -3.0e38f;
      }
    // online softmax per q: 16 in-reg + xor16 + xor32 (validated)
    float mx = sa[0][0];
    #pragma unroll
    for (int st = 0; st < 4; ++st)
      #pragma unroll
      for (int r = 0; r < 4; ++r) mx = fmaxf(mx, sa[st][r]);
    mx = fmaxf(mx, __shfl_xor(mx, 16));
    mx = fmaxf(mx, __shfl_xor(mx, 32));
    float mnew  = fmaxf(mrun, mx);
    float alpha = __expf(mrun - mnew);
    float ts = 0.f;
    ushort pb[16];
    #pragma unroll
    for (int st = 0; st < 4; ++st)
      #pragma unroll
      for (int r = 0; r < 4; ++r) {
        float p = __expf(sa[st][r] - mnew);
        ts += p;
        pb[st*4 + r] = f2bf(p);
      }
    ts += __shfl_xor(ts, 16);
    ts += __shfl_xor(ts, 32);
    lrun = lrun * alpha + ts;
    mrun = mnew;
    // alpha lives per q=lane&15; yacc rows are q=4*grp+r -> lane shuffle (validated)
    float ar[4];
    #pragma unroll
    for (int r = 0; r < 4; ++r) ar[r] = __shfl(alpha, 4*grp + r, 64);
    #pragma unroll
    for (int dt = 0; dt < 4; ++dt) {
      yacc[dt][0] *= ar[0]; yacc[dt][1] *= ar[1];
      yacc[dt][2] *= ar[2]; yacc[dt][3] *= ar[3];
    }
    // P -> LDS (bf16, row-major P[q][key]) (validated)
    #pragma unroll
    for (int st = 0; st < 4; ++st) {
      uint2 v;
      v.x = (uint)pb[st*4+0] | ((uint)pb[st*4+1] << 16);
      v.y = (uint)pb[st*4+2] | ((uint)pb[st*4+3] << 16);
      *(uint2*)&psw[q16*72 + 16*st + 4*grp] = v;
    }
    __threadfence_block();
    __builtin_amdgcn_sched_barrier(0);
    // PV: A = P (same lane->k map as write), B = U (validated)
    #pragma unroll
    for (int ks = 0; ks < 2; ++ks) {
      bf16x8 pa = *(const bf16x8*)&psw[q16*72 + 32*ks + colb];
      #pragma unroll
      for (int dt = 0; dt < 4; ++dt) {
        bf16x8 ub = *(const bf16x8*)&UTb[(16*dt + q16)*NCTX + j0 + 32*ks + colb];
        yacc[dt] = __builtin_amdgcn_mfma_f32_16x16x32_bf16(pa, ub, yacc[dt], 0,0,0);
      }
    }
  }
  // partials, green row-major layout (empty chunks: m=-3e38, l=0, y=0)
  if (grp == 0) {
    Pm[c * NCTX + q] = mrun;
    Pl[c * NCTX + q] = lrun;
  }
  #pragma unroll
  for (int dt = 0; dt < 4; ++dt)
    #pragma unroll
    for (int r = 0; r < 4; ++r)
      Py[(c * NCTX + q0 + 4*grp + r) * DH + 16*dt + q16] = yacc[dt][r];
}

// ---------------- combine (green, generalized to 8 chunks) ----------------
__global__ __launch_bounds__(256) void combine_kernel(
    const float* __restrict__ Pm, const float* __restrict__ Pl,
    const float* __restrict__ Py, float* __restrict__ Y)
{
  int idx = blockIdx.x * 256 + threadIdx.x;   // 0..262143
  int r = idx >> 6, d = idx & 63;
  float mv[NCH];
  float M = -3.0e38f;
  #pragma unroll
  for (int c = 0; c < NCH; ++c) {
    mv[c] = Pm[c*NCTX + r];
    M = fmaxf(M, mv[c]);
  }
  float num = 0.f, den = 0.f;
  #pragma unroll
  for (int c = 0; c < NCH; ++c) {
    float s = __expf(mv[c] - M);   // 0 for empty chunks
    den += s * Pl[c*NCTX + r];
    num += s * Py[(c*NCTX + r)*DH + d];
  }
  Y[idx] = num / den;
}

// ---------------- epilogue: out = Y @ W_vT (green, unchanged) ----------------
__global__ __launch_bounds__(256) void out_kernel(
    const float* __restrict__ Y, const float* __restrict__ Wv,
    float* __restrict__ out)
{
  __shared__ float Ws[64][256];
  __shared__ float YsT[64][64];
  const int tid = threadIdx.x;
  const int r0  = blockIdx.x * 64;
  const int cb  = blockIdx.y;
  const int c4  = tid & 63;
  const int rg  = __builtin_amdgcn_readfirstlane(tid >> 6);

  #pragma unroll
  for (int it = 0; it < 16; ++it) {
    int idx = it * 256 + tid;
    int h = idx >> 6, cc = idx & 63;
    *(float4*)&Ws[h][cc * 4] = *(const float4*)&Wv[h * DM + cb * 256 + cc * 4];
  }
  #pragma unroll
  for (int it = 0; it < 4; ++it) {
    int idx = it * 256 + tid;
    int h4 = idx & 15, rr = idx >> 4;
    float4 yv = *(const float4*)&Y[(r0 + rr) * DH + h4 * 4];
    YsT[h4*4+0][rr] = yv.x; YsT[h4*4+1][rr] = yv.y;
    YsT[h4*4+2][rr] = yv.z; YsT[h4*4+3][rr] = yv.w;
  }
  __syncthreads();

  float4 acc[16];
  #pragma unroll
  for (int i = 0; i < 16; ++i) acc[i] = make_float4(0.f, 0.f, 0.f, 0.f);

  #pragma unroll 8
  for (int h = 0; h < 64; ++h) {
    float4 w4 = *(const float4*)&Ws[h][c4 * 4];
    #pragma unroll
    for (int gq = 0; gq < 4; ++gq) {
      float4 y4 = *(const float4*)&YsT[h][rg * 16 + gq * 4];
      float ys[4] = {y4.x, y4.y, y4.z, y4.w};
      #pragma unroll
      for (int e = 0; e < 4; ++e) {
        acc[gq*4+e].x += ys[e] * w4.x;
        acc[gq*4+e].y += ys[e] * w4.y;
        acc[gq*4+e].z += ys[e] * w4.z;
        acc[gq*4+e].w += ys[e] * w4.w;
      }
    }
  }
  #pragma unroll
  for (int i = 0; i < 16; ++i)
    *(float4*)&out[(r0 + rg * 16 + i) * DM + cb * 256 + c4 * 4] = acc[i];
}

extern "C" void kernel_launch(void* const* d_in, const int* in_sizes, int n_in,
                              void* d_out, int out_size, void* d_ws, size_t ws_size,
                              hipStream_t stream) {
  const float* x   = (const float*)d_in[0];
  const float* Wq  = (const float*)d_in[1];
  const float* WkT = (const float*)d_in[2];
  const float* Wo  = (const float*)d_in[3];
  const float* Wv  = (const float*)d_in[4];
  float* out = (float*)d_out;
  float* ws  = (float*)d_ws;
  char*  ob  = (char*)d_out;   // scratch; fully overwritten by out_kernel

  float* Q   = ws + WS_Q;
  float* Kc  = ws + WS_K;
  float* UT  = ws + WS_U;
  float* Y   = ws + WS_Y;
  float* Wk  = ws + WS_WK;

  ushort* Qhp = (ushort*)(ob + D_QH);
  ushort* Qmp = (ushort*)(ob + D_QM);
  ushort* Qlp = (ushort*)(ob + D_QL);
  ushort* Khp = (ushort*)(ob + D_KH);
  ushort* Kmp = (ushort*)(ob + D_KM);
  ushort* Klp = (ushort*)(ob + D_KL);
  ushort* UTb = (ushort*)(ob + D_UTB);
  float*  Pyp = (float*)(ob + D_PY);
  float*  Pmp = (float*)(ob + D_PM);
  float*  Plp = (float*)(ob + D_PL);

  hipLaunchKernelGGL(wk_transpose_kernel, dim3(256), dim3(256), 0, stream, WkT, Wk);
  hipLaunchKernelGGL(proj_kernel, dim3(128, 3), dim3(256), 0, stream,
                     x, Wq, Wk, Wo, Q, Kc, UT);
  hipLaunchKernelGGL(split_kernel, dim3(1024), dim3(256), 0, stream,
                     Q, Kc, UT, Qhp, Qmp, Qlp, Khp, Kmp, Klp, UTb);
  hipLaunchKernelGGL(attn_kernel, dim3(512), dim3(256), 0, stream,
                     Qhp, Qmp, Qlp, Khp, Kmp, Klp, UTb, Pmp, Plp, Pyp);
  hipLaunchKernelGGL(combine_kernel, dim3(1024), dim3(256), 0, stream,
                     Pmp, Plp, Pyp, Y);
  hipLaunchKernelGGL(out_kernel, dim3(64, 4), dim3(256), 0, stream, Y, Wv, out);
}

// Round 11
// 114.237 us; speedup vs baseline: 3.4166x; 1.6053x over previous
//
#include <hip/hip_runtime.h>
#include <hip/hip_bf16.h>
#include <math.h>

#define DM    1024
#define DH    64
#define NCTX  4096
#define NCH   8        // key-chunks per q-group

typedef __attribute__((ext_vector_type(8))) short bf16x8;
typedef __attribute__((ext_vector_type(4))) float f32x4;

// ---- ws (proven 4,456,448 B): f32 Q, K, UT, Y (round-2 layout; WK slot unused)
#define WS_Q   0
#define WS_K   (NCTX*DH)
#define WS_U   (2*NCTX*DH)
#define WS_Y   (3*NCTX*DH)

// ---- d_out scratch (16 MiB, fully overwritten by out_kernel last)
#define D_QH   0          // 512 KiB each: bf16 digit arrays
#define D_QM   524288
#define D_QL   1048576
#define D_KH   1572864
#define D_KM   2097152
#define D_KL   2621440
#define D_UTB  3145728    // 512 KiB bf16 UT
#define D_PY   3670016    // 8 MiB f32 Py [NCH][NCTX][DH]
#define D_PM   12058624   // 128 KiB f32 [NCH][NCTX]
#define D_PL   12189696   // 128 KiB f32  (end 12320768)
#define D_WTH  12320768   // 384 KiB bf16 WT high digits [3][64][1024]
#define D_WTM  12713984   // 384 KiB bf16 WT mid digits   (end 13107200 < 16 MiB)

__device__ __forceinline__ ushort f2bf(float x) {
  __hip_bfloat16 h = __float2bfloat16(x);
  return __builtin_bit_cast(ushort, h);
}
__device__ __forceinline__ float bf2f(ushort u) {
  __hip_bfloat16 h = __builtin_bit_cast(__hip_bfloat16, u);
  return __bfloat162float(h);
}

// ---------------- W -> WT digit split: WTh/WTm [mat][64][1024] ----------------
// mat 1 (W_kT) is already [64][1024]; mats 0/2 transpose via (k,h) decode
// (coalesced reads, scattered 2B writes — 1.5 MB total, negligible).
__global__ __launch_bounds__(256) void wsplit_kernel(
    const float* __restrict__ Wq, const float* __restrict__ WkT,
    const float* __restrict__ Wo,
    ushort* __restrict__ WTh, ushort* __restrict__ WTm)
{
  int gid = blockIdx.x * 256 + threadIdx.x;   // 0..196607
  int mat = gid >> 16;
  int idx = gid & 65535;
  float v; int oidx;
  if (mat == 1) {
    v = WkT[idx];                 // already [h][k]
    oidx = 65536 + idx;
  } else {
    int k = idx >> 6, h = idx & 63;             // read coalesced: W[k][h] = W[idx]
    v = (mat == 0 ? Wq : Wo)[idx];
    oidx = mat * 65536 + h * 1024 + k;
  }
  ushort h16 = f2bf(v);
  float rem = v - bf2f(h16);
  WTh[oidx] = h16;
  WTm[oidx] = f2bf(rem);
}

// ---------------- projections via MFMA (validated operand pattern) ----------------
// grid (256 row-groups, 3 mats) x 64 threads (1 wave/block -> all CUs busy).
// Wave: 16 x-rows x 64 W-cols. x split to (h,m) digits in-register; 4 products.
// mats 0/1: A = x (D-row = x-row), B = WT (D-col = W-col)  -> Q/K row-major.
// mat  2  : A = WT, B = x  -> D[wcol][xrow] -> UT[col][row] contiguous writes.
__global__ __launch_bounds__(64) void proj_mfma_kernel(
    const float* __restrict__ x,
    const ushort* __restrict__ WTh, const ushort* __restrict__ WTm,
    float* __restrict__ Q, float* __restrict__ Kc, float* __restrict__ UT)
{
  const int lane = threadIdx.x;
  const int q16  = lane & 15;
  const int grp  = lane >> 4;
  const int colb = grp * 8;
  const int r0   = blockIdx.x * 16;
  const int mat  = blockIdx.y;
  const ushort* __restrict__ wh = WTh + mat * 65536;
  const ushort* __restrict__ wm = WTm + mat * 65536;

  f32x4 acc[4] = {{0,0,0,0},{0,0,0,0},{0,0,0,0},{0,0,0,0}};

  for (int ks = 0; ks < 32; ++ks) {
    const int xb = (r0 + q16) * DM + 32 * ks + colb;
    float4 a0 = *(const float4*)&x[xb];
    float4 a1 = *(const float4*)&x[xb + 4];
    float xv[8] = {a0.x, a0.y, a0.z, a0.w, a1.x, a1.y, a1.z, a1.w};
    bf16x8 xh8, xm8;
    #pragma unroll
    for (int e = 0; e < 8; ++e) {
      ushort h = f2bf(xv[e]);
      float rem = xv[e] - bf2f(h);
      xh8[e] = (short)h;
      xm8[e] = (short)f2bf(rem);
    }
    if (mat == 2) {
      #pragma unroll
      for (int ct = 0; ct < 4; ++ct) {
        const int wb = (16 * ct + q16) * DM + 32 * ks + colb;
        bf16x8 bh = *(const bf16x8*)&wh[wb];
        bf16x8 bm = *(const bf16x8*)&wm[wb];
        acc[ct] = __builtin_amdgcn_mfma_f32_16x16x32_bf16(bh, xh8, acc[ct], 0,0,0);
        acc[ct] = __builtin_amdgcn_mfma_f32_16x16x32_bf16(bh, xm8, acc[ct], 0,0,0);
        acc[ct] = __builtin_amdgcn_mfma_f32_16x16x32_bf16(bm, xh8, acc[ct], 0,0,0);
        acc[ct] = __builtin_amdgcn_mfma_f32_16x16x32_bf16(bm, xm8, acc[ct], 0,0,0);
      }
    } else {
      #pragma unroll
      for (int ct = 0; ct < 4; ++ct) {
        const int wb = (16 * ct + q16) * DM + 32 * ks + colb;
        bf16x8 bh = *(const bf16x8*)&wh[wb];
        bf16x8 bm = *(const bf16x8*)&wm[wb];
        acc[ct] = __builtin_amdgcn_mfma_f32_16x16x32_bf16(xh8, bh, acc[ct], 0,0,0);
        acc[ct] = __builtin_amdgcn_mfma_f32_16x16x32_bf16(xh8, bm, acc[ct], 0,0,0);
        acc[ct] = __builtin_amdgcn_mfma_f32_16x16x32_bf16(xm8, bh, acc[ct], 0,0,0);
        acc[ct] = __builtin_amdgcn_mfma_f32_16x16x32_bf16(xm8, bm, acc[ct], 0,0,0);
      }
    }
  }

  if (mat == 2) {
    // D[wcol = 16ct+4grp+r][xrow = r0+q16] -> UT[col][row]
    #pragma unroll
    for (int ct = 0; ct < 4; ++ct)
      #pragma unroll
      for (int r = 0; r < 4; ++r)
        UT[(16*ct + 4*grp + r) * NCTX + r0 + q16] = acc[ct][r];
  } else {
    float* __restrict__ Out = (mat == 0) ? Q : Kc;
    // D[xrow = r0+4grp+r][wcol = 16ct+q16] (validated Py-write pattern)
    #pragma unroll
    for (int ct = 0; ct < 4; ++ct)
      #pragma unroll
      for (int r = 0; r < 4; ++r)
        Out[(r0 + 4*grp + r) * DH + 16*ct + q16] = acc[ct][r];
  }
}

// ---------------- 3-way bf16 digit split (validated) ----------------
__global__ __launch_bounds__(256) void split_kernel(
    const float* __restrict__ Q, const float* __restrict__ K, const float* __restrict__ UT,
    ushort* __restrict__ Qh, ushort* __restrict__ Qm, ushort* __restrict__ Ql,
    ushort* __restrict__ Kh, ushort* __restrict__ Km, ushort* __restrict__ Kl,
    ushort* __restrict__ UTb)
{
  int i = blockIdx.x * 256 + threadIdx.x;
  float q = Q[i];
  ushort h = f2bf(q); float fh = bf2f(h);
  ushort m = f2bf(q - fh); float fm = bf2f(m);
  ushort l = f2bf(q - fh - fm);
  Qh[i] = h; Qm[i] = m; Ql[i] = l;
  float k = K[i];
  h = f2bf(k); fh = bf2f(h);
  m = f2bf(k - fh); fm = bf2f(m);
  l = f2bf(k - fh - fm);
  Kh[i] = h; Km[i] = m; Kl[i] = l;
  UTb[i] = f2bf(UT[i]);
}

// ---------------- MFMA flash attention (validated, unchanged) ----------------
__global__ __launch_bounds__(256) void attn_kernel(
    const ushort* __restrict__ Qh, const ushort* __restrict__ Qm, const ushort* __restrict__ Ql,
    const ushort* __restrict__ Kh, const ushort* __restrict__ Km, const ushort* __restrict__ Kl,
    const ushort* __restrict__ UTb,
    float* __restrict__ Pm, float* __restrict__ Pl, float* __restrict__ Py)
{
  __shared__ __align__(16) ushort ps[4][16*72];
  const int tid  = threadIdx.x;
  const int lane = tid & 63;
  const int w    = tid >> 6;
  ushort* psw = ps[w];
  const int q16  = lane & 15;
  const int grp  = lane >> 4;
  const int colb = grp * 8;

  const int u  = blockIdx.x * 4 + w;
  const int g  = 255 - (u >> 3);
  const int c  = u & 7;
  const int Tg = ((16*g + 15) >> 6) + 1;
  const int t0 = (c * Tg) >> 3, t1 = ((c+1) * Tg) >> 3;
  const int q0 = 16 * g;
  const int q  = q0 + q16;

  bf16x8 fqh[2], fqm[2], fql[2];
  #pragma unroll
  for (int ks = 0; ks < 2; ++ks) {
    int off = (q0 + q16)*DH + 32*ks + colb;
    fqh[ks] = *(const bf16x8*)&Qh[off];
    fqm[ks] = *(const bf16x8*)&Qm[off];
    fql[ks] = *(const bf16x8*)&Ql[off];
  }

  float mrun = -3.0e38f, lrun = 0.f;
  f32x4 yacc[4] = {{0,0,0,0},{0,0,0,0},{0,0,0,0},{0,0,0,0}};

  for (int t = t0; t < t1; ++t) {
    const int j0 = t * 64;
    f32x4 sa[4];
    #pragma unroll
    for (int st = 0; st < 4; ++st) {
      f32x4 acc = {0,0,0,0};
      #pragma unroll
      for (int ks = 0; ks < 2; ++ks) {
        int off = (j0 + 16*st + q16)*DH + 32*ks + colb;
        bf16x8 kh = *(const bf16x8*)&Kh[off];
        bf16x8 km = *(const bf16x8*)&Km[off];
        bf16x8 kl = *(const bf16x8*)&Kl[off];
        acc = __builtin_amdgcn_mfma_f32_16x16x32_bf16(kh, fqh[ks], acc, 0,0,0);
        acc = __builtin_amdgcn_mfma_f32_16x16x32_bf16(kh, fqm[ks], acc, 0,0,0);
        acc = __builtin_amdgcn_mfma_f32_16x16x32_bf16(km, fqh[ks], acc, 0,0,0);
        acc = __builtin_amdgcn_mfma_f32_16x16x32_bf16(km, fqm[ks], acc, 0,0,0);
        acc = __builtin_amdgcn_mfma_f32_16x16x32_bf16(kh, fql[ks], acc, 0,0,0);
        acc = __builtin_amdgcn_mfma_f32_16x16x32_bf16(kl, fqh[ks], acc, 0,0,0);
      }
      sa[st] = acc;
    }
    #pragma unroll
    for (int st = 0; st < 4; ++st)
      #pragma unroll
      for (int r = 0; r < 4; ++r) {
        int key = j0 + 16*st + 4*grp + r;
        if (key > q) sa[st][r] = -3.0e38f;
      }
    float mx = sa[0][0];
    #pragma unroll
    for (int st = 0; st < 4; ++st)
      #pragma unroll
      for (int r = 0; r < 4; ++r) mx = fmaxf(mx, sa[st][r]);
    mx = fmaxf(mx, __shfl_xor(mx, 16));
    mx = fmaxf(mx, __shfl_xor(mx, 32));
    float mnew  = fmaxf(mrun, mx);
    float alpha = __expf(mrun - mnew);
    float ts = 0.f;
    ushort pb[16];
    #pragma unroll
    for (int st = 0; st < 4; ++st)
      #pragma unroll
      for (int r = 0; r < 4; ++r) {
        float p = __expf(sa[st][r] - mnew);
        ts += p;
        pb[st*4 + r] = f2bf(p);
      }
    ts += __shfl_xor(ts, 16);
    ts += __shfl_xor(ts, 32);
    lrun = lrun * alpha + ts;
    mrun = mnew;
    float ar[4];
    #pragma unroll
    for (int r = 0; r < 4; ++r) ar[r] = __shfl(alpha, 4*grp + r, 64);
    #pragma unroll
    for (int dt = 0; dt < 4; ++dt) {
      yacc[dt][0] *= ar[0]; yacc[dt][1] *= ar[1];
      yacc[dt][2] *= ar[2]; yacc[dt][3] *= ar[3];
    }
    #pragma unroll
    for (int st = 0; st < 4; ++st) {
      uint2 v;
      v.x = (uint)pb[st*4+0] | ((uint)pb[st*4+1] << 16);
      v.y = (uint)pb[st*4+2] | ((uint)pb[st*4+3] << 16);
      *(uint2*)&psw[q16*72 + 16*st + 4*grp] = v;
    }
    __threadfence_block();
    __builtin_amdgcn_sched_barrier(0);
    #pragma unroll
    for (int ks = 0; ks < 2; ++ks) {
      bf16x8 pa = *(const bf16x8*)&psw[q16*72 + 32*ks + colb];
      #pragma unroll
      for (int dt = 0; dt < 4; ++dt) {
        bf16x8 ub = *(const bf16x8*)&UTb[(16*dt + q16)*NCTX + j0 + 32*ks + colb];
        yacc[dt] = __builtin_amdgcn_mfma_f32_16x16x32_bf16(pa, ub, yacc[dt], 0,0,0);
      }
    }
  }
  if (grp == 0) {
    Pm[c * NCTX + q] = mrun;
    Pl[c * NCTX + q] = lrun;
  }
  #pragma unroll
  for (int dt = 0; dt < 4; ++dt)
    #pragma unroll
    for (int r = 0; r < 4; ++r)
      Py[(c * NCTX + q0 + 4*grp + r) * DH + 16*dt + q16] = yacc[dt][r];
}

// ---------------- combine (validated, unchanged) ----------------
__global__ __launch_bounds__(256) void combine_kernel(
    const float* __restrict__ Pm, const float* __restrict__ Pl,
    const float* __restrict__ Py, float* __restrict__ Y)
{
  int idx = blockIdx.x * 256 + threadIdx.x;
  int r = idx >> 6, d = idx & 63;
  float mv[NCH];
  float M = -3.0e38f;
  #pragma unroll
  for (int c = 0; c < NCH; ++c) {
    mv[c] = Pm[c*NCTX + r];
    M = fmaxf(M, mv[c]);
  }
  float num = 0.f, den = 0.f;
  #pragma unroll
  for (int c = 0; c < NCH; ++c) {
    float s = __expf(mv[c] - M);
    den += s * Pl[c*NCTX + r];
    num += s * Py[(c*NCTX + r)*DH + d];
  }
  Y[idx] = num / den;
}

// ---------------- epilogue: out = Y @ W_vT (validated, unchanged) ----------------
__global__ __launch_bounds__(256) void out_kernel(
    const float* __restrict__ Y, const float* __restrict__ Wv,
    float* __restrict__ out)
{
  __shared__ float Ws[64][256];
  __shared__ float YsT[64][64];
  const int tid = threadIdx.x;
  const int r0  = blockIdx.x * 64;
  const int cb  = blockIdx.y;
  const int c4  = tid & 63;
  const int rg  = __builtin_amdgcn_readfirstlane(tid >> 6);

  #pragma unroll
  for (int it = 0; it < 16; ++it) {
    int idx = it * 256 + tid;
    int h = idx >> 6, cc = idx & 63;
    *(float4*)&Ws[h][cc * 4] = *(const float4*)&Wv[h * DM + cb * 256 + cc * 4];
  }
  #pragma unroll
  for (int it = 0; it < 4; ++it) {
    int idx = it * 256 + tid;
    int h4 = idx & 15, rr = idx >> 4;
    float4 yv = *(const float4*)&Y[(r0 + rr) * DH + h4 * 4];
    YsT[h4*4+0][rr] = yv.x; YsT[h4*4+1][rr] = yv.y;
    YsT[h4*4+2][rr] = yv.z; YsT[h4*4+3][rr] = yv.w;
  }
  __syncthreads();

  float4 acc[16];
  #pragma unroll
  for (int i = 0; i < 16; ++i) acc[i] = make_float4(0.f, 0.f, 0.f, 0.f);

  #pragma unroll 8
  for (int h = 0; h < 64; ++h) {
    float4 w4 = *(const float4*)&Ws[h][c4 * 4];
    #pragma unroll
    for (int gq = 0; gq < 4; ++gq) {
      float4 y4 = *(const float4*)&YsT[h][rg * 16 + gq * 4];
      float ys[4] = {y4.x, y4.y, y4.z, y4.w};
      #pragma unroll
      for (int e = 0; e < 4; ++e) {
        acc[gq*4+e].x += ys[e] * w4.x;
        acc[gq*4+e].y += ys[e] * w4.y;
        acc[gq*4+e].z += ys[e] * w4.z;
        acc[gq*4+e].w += ys[e] * w4.w;
      }
    }
  }
  #pragma unroll
  for (int i = 0; i < 16; ++i)
    *(float4*)&out[(r0 + rg * 16 + i) * DM + cb * 256 + c4 * 4] = acc[i];
}

extern "C" void kernel_launch(void* const* d_in, const int* in_sizes, int n_in,
                              void* d_out, int out_size, void* d_ws, size_t ws_size,
                              hipStream_t stream) {
  const float* x   = (const float*)d_in[0];
  const float* Wq  = (const float*)d_in[1];
  const float* WkT = (const float*)d_in[2];
  const float* Wo  = (const float*)d_in[3];
  const float* Wv  = (const float*)d_in[4];
  float* out = (float*)d_out;
  float* ws  = (float*)d_ws;
  char*  ob  = (char*)d_out;   // scratch; fully overwritten by out_kernel

  float* Q   = ws + WS_Q;
  float* Kc  = ws + WS_K;
  float* UT  = ws + WS_U;
  float* Y   = ws + WS_Y;

  ushort* Qhp = (ushort*)(ob + D_QH);
  ushort* Qmp = (ushort*)(ob + D_QM);
  ushort* Qlp = (ushort*)(ob + D_QL);
  ushort* Khp = (ushort*)(ob + D_KH);
  ushort* Kmp = (ushort*)(ob + D_KM);
  ushort* Klp = (ushort*)(ob + D_KL);
  ushort* UTb = (ushort*)(ob + D_UTB);
  float*  Pyp = (float*)(ob + D_PY);
  float*  Pmp = (float*)(ob + D_PM);
  float*  Plp = (float*)(ob + D_PL);
  ushort* WTh = (ushort*)(ob + D_WTH);
  ushort* WTm = (ushort*)(ob + D_WTM);

  hipLaunchKernelGGL(wsplit_kernel, dim3(768), dim3(256), 0, stream,
                     Wq, WkT, Wo, WTh, WTm);
  hipLaunchKernelGGL(proj_mfma_kernel, dim3(256, 3), dim3(64), 0, stream,
                     x, WTh, WTm, Q, Kc, UT);
  hipLaunchKernelGGL(split_kernel, dim3(1024), dim3(256), 0, stream,
                     Q, Kc, UT, Qhp, Qmp, Qlp, Khp, Kmp, Klp, UTb);
  hipLaunchKernelGGL(attn_kernel, dim3(512), dim3(256), 0, stream,
                     Qhp, Qmp, Qlp, Khp, Kmp, Klp, UTb, Pmp, Plp, Pyp);
  hipLaunchKernelGGL(combine_kernel, dim3(1024), dim3(256), 0, stream,
                     Pmp, Plp, Pyp, Y);
  hipLaunchKernelGGL(out_kernel, dim3(64, 4), dim3(256), 0, stream, Y, Wv, out);
}